// Round 2
// baseline (10615.767 us; speedup 1.0000x reference)
//
#include <hip/hip_runtime.h>
#include <hip/hip_bf16.h>

// Problem constants
#define BB 4
#define TT 2048
#define TRAIN 1536
#define DD 512
#define HH 8
#define LL 12
#define FFD 2048
#define VV 100
#define DH 64
#define NT (BB*TT)            // 8192 tokens
#define NTEST (BB*(TT-TRAIN)) // 2048 test rows

typedef __bf16 bf16x8 __attribute__((ext_vector_type(8)));
typedef float  f32x4  __attribute__((ext_vector_type(4)));

// ---------------------------------------------------------------- emb + R add
__global__ __launch_bounds__(256) void emb_add(const float* __restrict__ R,
                                               const int* __restrict__ y,
                                               const float* __restrict__ emb,
                                               float* __restrict__ rep) {
    int idx = blockIdx.x * 256 + threadIdx.x;            // NT*DD total
    int d = idx & 511;
    int n = idx >> 9;
    int t = n & (TT - 1);
    int b = n >> 11;
    float val = R[idx];
    if (t < TRAIN) {
        int tok = y[b * TRAIN + t];
        val += emb[(size_t)tok * DD + d];
    }
    rep[idx] = val;
}

// ---------------------------------------------------------------- layernorm (fp32 in, bf16 out)
__global__ __launch_bounds__(256) void ln_kernel(const float* __restrict__ x,
                                                 const float* __restrict__ g,
                                                 const float* __restrict__ bta,
                                                 __bf16* __restrict__ out) {
    int row = blockIdx.x;
    int tid = threadIdx.x;
    const float* xr = x + (size_t)row * DD;
    float v0 = xr[tid], v1 = xr[tid + 256];
    float s = v0 + v1;
    float sq = v0 * v0 + v1 * v1;
#pragma unroll
    for (int off = 32; off; off >>= 1) {
        s  += __shfl_down(s, off);
        sq += __shfl_down(sq, off);
    }
    __shared__ float ss[4], ssq[4];
    if ((tid & 63) == 0) { ss[tid >> 6] = s; ssq[tid >> 6] = sq; }
    __syncthreads();
    float S  = ss[0] + ss[1] + ss[2] + ss[3];
    float SQ = ssq[0] + ssq[1] + ssq[2] + ssq[3];
    float mu  = S * (1.0f / DD);
    float var = SQ * (1.0f / DD) - mu * mu;
    float inv = rsqrtf(var + 1e-5f);
    __bf16* orow = out + (size_t)row * DD;
    orow[tid]       = (__bf16)((v0 - mu) * inv * g[tid]       + bta[tid]);
    orow[tid + 256] = (__bf16)((v1 - mu) * inv * g[tid + 256] + bta[tid + 256]);
}

// ---------------------------------------------------------------- rope table
__global__ __launch_bounds__(256) void rope_tab(float* __restrict__ ctab, float* __restrict__ stab) {
    int idx = blockIdx.x * 256 + threadIdx.x;  // TT*32
    int p = idx & 31, t = idx >> 5;
    double freq = exp(-((double)(2 * p) / 64.0) * log(100000.0));
    double ang = (double)t * freq;
    ctab[idx] = (float)cos(ang);
    stab[idx] = (float)sin(ang);
}

// ------------------------------------------- qkv split + rope -> [B,H,T,DH]
__global__ __launch_bounds__(256) void rope_split(const __bf16* __restrict__ qkv,
                                                  const float* __restrict__ ctab,
                                                  const float* __restrict__ stab,
                                                  __bf16* __restrict__ qo,
                                                  __bf16* __restrict__ ko,
                                                  __bf16* __restrict__ vo) {
    int idx = blockIdx.x * 256 + threadIdx.x;  // BB*TT*HH*32
    int p = idx & 31;
    int rest = idx >> 5;
    int h = rest & 7;  rest >>= 3;
    int t = rest & (TT - 1);
    int b = rest >> 11;
    const __bf16* base = qkv + (size_t)(b * TT + t) * (3 * DD) + h * DH;
    float c = ctab[t * 32 + p], s = stab[t * 32 + p];
    float x1 = (float)base[2 * p],       x2 = (float)base[2 * p + 1];
    float k1 = (float)base[DD + 2 * p],  k2 = (float)base[DD + 2 * p + 1];
    size_t ob = ((size_t)(b * HH + h) * TT + t) * DH;
    qo[ob + 2 * p]     = (__bf16)(x1 * c - x2 * s);
    qo[ob + 2 * p + 1] = (__bf16)(x1 * s + x2 * c);
    ko[ob + 2 * p]     = (__bf16)(k1 * c - k2 * s);
    ko[ob + 2 * p + 1] = (__bf16)(k1 * s + k2 * c);
    vo[ob + 2 * p]     = base[2 * DD + 2 * p];
    vo[ob + 2 * p + 1] = base[2 * DD + 2 * p + 1];
}

// ---------------------------------------------------------------- attention
// One thread per query. Keys = all TRAIN keys + self (for t>=TRAIN).
__global__ __launch_bounds__(256) void attn_kernel(const __bf16* __restrict__ q,
                                                   const __bf16* __restrict__ k,
                                                   const __bf16* __restrict__ v,
                                                   __bf16* __restrict__ obuf) {
    __shared__ float Ks[64 * 64];
    __shared__ float Vs[64 * 64];
    const int tid = threadIdx.x;
    const int bh = blockIdx.y;
    const int tq = blockIdx.x * 256 + tid;
    const int b = bh >> 3, hh = bh & 7;
    const size_t kbase = (size_t)bh * TT * DH;

    float qr[64];
    {
        const __bf16* qp = q + kbase + (size_t)tq * DH;
#pragma unroll
        for (int i = 0; i < 8; ++i) {
            uint4 u = *(const uint4*)&qp[i * 8];
            const __bf16* pb = (const __bf16*)&u;
#pragma unroll
            for (int j = 0; j < 8; ++j) qr[i * 8 + j] = (float)pb[j];
        }
    }
    float o[64] = {};
    float m = -1e30f, l = 0.f;

    for (int st = 0; st < TRAIN; st += 64) {
#pragma unroll
        for (int c = 0; c < 2; ++c) {
            int ch = tid + c * 256;
            int r = ch >> 3, c8 = (ch & 7) * 8;
            uint4 uk = *(const uint4*)&k[kbase + (size_t)(st + r) * DH + c8];
            uint4 uv = *(const uint4*)&v[kbase + (size_t)(st + r) * DH + c8];
            const __bf16* pk = (const __bf16*)&uk;
            const __bf16* pv = (const __bf16*)&uv;
#pragma unroll
            for (int j = 0; j < 8; ++j) {
                Ks[r * 64 + c8 + j] = (float)pk[j];
                Vs[r * 64 + c8 + j] = (float)pv[j];
            }
        }
        __syncthreads();
        for (int s = 0; s < 64; ++s) {
            const float* kr = &Ks[s * 64];
            float s0 = 0, s1 = 0, s2 = 0, s3 = 0;
#pragma unroll
            for (int d = 0; d < 64; d += 4) {
                s0 += qr[d] * kr[d];
                s1 += qr[d + 1] * kr[d + 1];
                s2 += qr[d + 2] * kr[d + 2];
                s3 += qr[d + 3] * kr[d + 3];
            }
            float sc = (s0 + s1 + s2 + s3) * 0.125f;
            if (sc > m) {
                float corr = __expf(m - sc);
                l *= corr;
#pragma unroll
                for (int d = 0; d < 64; ++d) o[d] *= corr;
                m = sc;
            }
            float p = __expf(sc - m);
            l += p;
            const float* vr = &Vs[s * 64];
#pragma unroll
            for (int d = 0; d < 64; ++d) o[d] += p * vr[d];
        }
        __syncthreads();
    }

    if (tq >= TRAIN) {  // self key (uniform per block: blocks 6,7)
        const __bf16* kp = k + kbase + (size_t)tq * DH;
        float s0 = 0, s1 = 0, s2 = 0, s3 = 0;
#pragma unroll
        for (int i = 0; i < 8; ++i) {
            uint4 uk = *(const uint4*)&kp[i * 8];
            const __bf16* pk = (const __bf16*)&uk;
#pragma unroll
            for (int j = 0; j < 8; ++j) {
                float kv = (float)pk[j];
                if ((j & 3) == 0) s0 += qr[i * 8 + j] * kv;
                else if ((j & 3) == 1) s1 += qr[i * 8 + j] * kv;
                else if ((j & 3) == 2) s2 += qr[i * 8 + j] * kv;
                else s3 += qr[i * 8 + j] * kv;
            }
        }
        float sc = (s0 + s1 + s2 + s3) * 0.125f;
        if (sc > m) {
            float corr = __expf(m - sc);
            l *= corr;
#pragma unroll
            for (int d = 0; d < 64; ++d) o[d] *= corr;
            m = sc;
        }
        float p = __expf(sc - m);
        l += p;
        const __bf16* vp = v + kbase + (size_t)tq * DH;
#pragma unroll
        for (int i = 0; i < 8; ++i) {
            uint4 uv = *(const uint4*)&vp[i * 8];
            const __bf16* pv = (const __bf16*)&uv;
#pragma unroll
            for (int j = 0; j < 8; ++j) o[i * 8 + j] += p * (float)pv[j];
        }
    }

    float inv = 1.f / l;
    __bf16* op = obuf + (size_t)(b * TT + tq) * DD + hh * DH;
#pragma unroll
    for (int d = 0; d < 64; ++d) op[d] = (__bf16)(o[d] * inv);
}

// ------------------------------------- transpose fp32->bf16 (with N-pad/zero-fill)
__global__ __launch_bounds__(256) void transpose_pad(const float* __restrict__ src,  // [K,N] fp32
                                                     __bf16* __restrict__ dst,       // [Npad,K] bf16
                                                     int K, int N) {
    __shared__ __bf16 t[32][33];
    int n0 = blockIdx.x * 32, k0 = blockIdx.y * 32;
    int tx = threadIdx.x & 31, ty = threadIdx.x >> 5;  // ty 0..7
#pragma unroll
    for (int i = 0; i < 4; ++i) {
        int nn = n0 + tx;
        t[ty + i * 8][tx] = (nn < N) ? (__bf16)src[(size_t)(k0 + ty + i * 8) * N + nn] : (__bf16)0.f;
    }
    __syncthreads();
#pragma unroll
    for (int i = 0; i < 4; ++i) {
        dst[(size_t)(n0 + ty + i * 8) * K + k0 + tx] = t[tx][ty + i * 8];
    }
}

// ---------------------------------------------------------------- MFMA GEMM (Bt input)
// C[M,N] = A[M,K] * B[K,N] + bias, with Bt = B^T given as [N,K] (bf16).
// EP=0: bf16 store; EP=1: gelu(tanh) then bf16 store; EP=2: resid += (fp32);
// EP=3: plain fp32 store to resid.
template <int EP>
__global__ __launch_bounds__(256) void gemm_bt(const __bf16* __restrict__ A,
                                               const __bf16* __restrict__ Bt,
                                               const float* __restrict__ bias,
                                               float* __restrict__ resid,
                                               __bf16* __restrict__ Cout,
                                               int M, int N, int K) {
    __shared__ __align__(16) __bf16 As[128 * 32];
    __shared__ __align__(16) __bf16 Bs[128 * 32];
    const int tid = threadIdx.x;
    const int m0 = blockIdx.x * 128;
    const int n0 = blockIdx.y * 128;
    const int lane = tid & 63;
    const int w = tid >> 6;
    const int wm = (w >> 1) * 64, wn = (w & 1) * 64;
    const int lrow = lane & 15;
    const int kq = (lane >> 4) * 8;

    f32x4 acc[4][4] = {};
    const int r0 = tid >> 2,         o0 = (tid & 3) * 8;
    const int r1 = (tid + 256) >> 2, o1 = o0;   // same (c&3) since +256 keeps low bits

    const int nk = K >> 5;
    for (int kt = 0; kt < nk; ++kt) {
        const int k0 = kt << 5;
        *(uint4*)&As[r0 * 32 + o0] = *(const uint4*)&A[(size_t)(m0 + r0) * K + k0 + o0];
        *(uint4*)&As[r1 * 32 + o1] = *(const uint4*)&A[(size_t)(m0 + r1) * K + k0 + o1];
        *(uint4*)&Bs[r0 * 32 + o0] = *(const uint4*)&Bt[(size_t)(n0 + r0) * K + k0 + o0];
        *(uint4*)&Bs[r1 * 32 + o1] = *(const uint4*)&Bt[(size_t)(n0 + r1) * K + k0 + o1];
        __syncthreads();
        bf16x8 afr[4], bfr[4];
#pragma unroll
        for (int i = 0; i < 4; ++i) {
            afr[i] = *(const bf16x8*)&As[(wm + i * 16 + lrow) * 32 + kq];
            bfr[i] = *(const bf16x8*)&Bs[(wn + i * 16 + lrow) * 32 + kq];
        }
#pragma unroll
        for (int mi = 0; mi < 4; ++mi)
#pragma unroll
            for (int ni = 0; ni < 4; ++ni)
                acc[mi][ni] = __builtin_amdgcn_mfma_f32_16x16x32_bf16(afr[mi], bfr[ni], acc[mi][ni], 0, 0, 0);
        __syncthreads();
    }

    const int crow = (lane >> 4) * 4;
    const int ccol = lane & 15;
#pragma unroll
    for (int mi = 0; mi < 4; ++mi) {
#pragma unroll
        for (int ni = 0; ni < 4; ++ni) {
            int gn = n0 + wn + ni * 16 + ccol;
            float bv = bias[gn];
#pragma unroll
            for (int r = 0; r < 4; ++r) {
                int gm = m0 + wm + mi * 16 + crow + r;
                float vvv = acc[mi][ni][r] + bv;
                if constexpr (EP == 1) {
                    float x = vvv;
                    vvv = 0.5f * x * (1.f + tanhf(0.7978845608f * (x + 0.044715f * x * x * x)));
                }
                if constexpr (EP == 2) {
                    resid[(size_t)gm * N + gn] += vvv;
                } else if constexpr (EP == 3) {
                    resid[(size_t)gm * N + gn] = vvv;
                } else {
                    Cout[(size_t)gm * N + gn] = (__bf16)vvv;
                }
            }
        }
    }
}

// ---------------------------------------------------------------- post-layer helpers
__global__ __launch_bounds__(256) void cast_test(const float* __restrict__ rep, __bf16* __restrict__ testb) {
    int idx = blockIdx.x * 256 + threadIdx.x;  // NTEST*DD
    int d = idx & 511;
    int i = idx >> 9;
    int ttk = i & 511;
    int b = i >> 9;
    testb[idx] = (__bf16)rep[(size_t)(b * TT + TRAIN + ttk) * DD + d];
}

__global__ void pad_bias(const float* __restrict__ pb2, float* __restrict__ pb2p) {
    int t = threadIdx.x;
    if (t < 128) pb2p[t] = (t < VV) ? pb2[t] : 0.f;
}

__global__ __launch_bounds__(256) void extract_out(const float* __restrict__ outpad, float* __restrict__ out) {
    int idx = blockIdx.x * 256 + threadIdx.x;  // NTEST*VV = 204800
    if (idx < NTEST * VV) {
        int i = idx / VV, j = idx - i * VV;
        out[idx] = outpad[i * 128 + j];
    }
}

// ---------------------------------------------------------------- launcher
extern "C" void kernel_launch(void* const* d_in, const int* in_sizes, int n_in,
                              void* d_out, int out_size, void* d_ws, size_t ws_size,
                              hipStream_t stream) {
    const float* R    = (const float*)d_in[0];
    const int*   y    = (const int*)d_in[1];
    const float* emb  = (const float*)d_in[2];
    const float* Wqkv = (const float*)d_in[3];
    const float* bqkv = (const float*)d_in[4];
    const float* Wo   = (const float*)d_in[5];
    const float* bo   = (const float*)d_in[6];
    const float* ln1g = (const float*)d_in[7];
    const float* ln1b = (const float*)d_in[8];
    const float* ln2g = (const float*)d_in[9];
    const float* ln2b = (const float*)d_in[10];
    const float* W1   = (const float*)d_in[11];
    const float* b1   = (const float*)d_in[12];
    const float* W2   = (const float*)d_in[13];
    const float* b2   = (const float*)d_in[14];
    const float* pW1  = (const float*)d_in[15];
    const float* pb1  = (const float*)d_in[16];
    const float* pW2  = (const float*)d_in[17];
    const float* pb2  = (const float*)d_in[18];

    // workspace carve-up
    char* p = (char*)d_ws;
    float* rep   = (float*)p;  p += (size_t)NT * DD * 4;        // 16.78 MB
    __bf16* hbuf = (__bf16*)p; p += (size_t)NT * DD * 2;        // 8.39 MB
    __bf16* qkv  = (__bf16*)p;                                  // union with ffb
    __bf16* ffb  = qkv;        p += (size_t)NT * FFD * 2;       // 33.55 MB
    __bf16* qb   = (__bf16*)p; p += (size_t)NT * DD * 2;        // 8.39 MB
    __bf16* kb   = (__bf16*)p; p += (size_t)NT * DD * 2;
    __bf16* vb   = (__bf16*)p; p += (size_t)NT * DD * 2;
    __bf16* obuf = (__bf16*)p; p += (size_t)NT * DD * 2;
    __bf16* wt   = (__bf16*)p; p += (size_t)2048 * 512 * 2;     // 2 MB transposed-weight scratch
    float* ctab  = (float*)p;  p += (size_t)TT * 32 * 4;
    float* stab  = (float*)p;  p += (size_t)TT * 32 * 4;
    float* pb2p  = (float*)p;  p += 512;
    // post-layer aliases (hbuf/qb/obuf dead after the layer loop)
    __bf16* testb  = hbuf;                 // 2 MB
    __bf16* hb     = obuf;                 // 4 MB
    float*  outpad = (float*)qb;           // 1 MB

    emb_add<<<NT * DD / 256, 256, 0, stream>>>(R, y, emb, rep);
    rope_tab<<<TT * 32 / 256, 256, 0, stream>>>(ctab, stab);

    for (int l = 0; l < LL; ++l) {
        ln_kernel<<<NT, 256, 0, stream>>>(rep, ln1g + l * DD, ln1b + l * DD, hbuf);
        transpose_pad<<<dim3(1536 / 32, 512 / 32), 256, 0, stream>>>(Wqkv + (size_t)l * DD * 3 * DD, wt, DD, 3 * DD);
        gemm_bt<0><<<dim3(NT / 128, 1536 / 128), 256, 0, stream>>>(hbuf, wt, bqkv + l * 3 * DD, nullptr, qkv, NT, 3 * DD, DD);
        rope_split<<<BB * TT * HH * 32 / 256, 256, 0, stream>>>(qkv, ctab, stab, qb, kb, vb);
        attn_kernel<<<dim3(TT / 256, BB * HH), 256, 0, stream>>>(qb, kb, vb, obuf);
        transpose_pad<<<dim3(512 / 32, 512 / 32), 256, 0, stream>>>(Wo + (size_t)l * DD * DD, wt, DD, DD);
        gemm_bt<2><<<dim3(NT / 128, 512 / 128), 256, 0, stream>>>(obuf, wt, bo + l * DD, rep, nullptr, NT, DD, DD);
        ln_kernel<<<NT, 256, 0, stream>>>(rep, ln2g + l * DD, ln2b + l * DD, hbuf);
        transpose_pad<<<dim3(2048 / 32, 512 / 32), 256, 0, stream>>>(W1 + (size_t)l * DD * FFD, wt, DD, FFD);
        gemm_bt<1><<<dim3(NT / 128, FFD / 128), 256, 0, stream>>>(hbuf, wt, b1 + l * FFD, nullptr, ffb, NT, FFD, DD);
        transpose_pad<<<dim3(512 / 32, 2048 / 32), 256, 0, stream>>>(W2 + (size_t)l * FFD * DD, wt, FFD, DD);
        gemm_bt<2><<<dim3(NT / 128, 512 / 128), 256, 0, stream>>>(ffb, wt, b2 + l * DD, rep, nullptr, NT, DD, FFD);
    }

    cast_test<<<NTEST * DD / 256, 256, 0, stream>>>(rep, testb);
    transpose_pad<<<dim3(1024 / 32, 512 / 32), 256, 0, stream>>>(pW1, wt, DD, 2 * DD);
    gemm_bt<1><<<dim3(NTEST / 128, 1024 / 128), 256, 0, stream>>>(testb, wt, pb1, nullptr, hb, NTEST, 2 * DD, DD);
    pad_bias<<<1, 128, 0, stream>>>(pb2, pb2p);
    transpose_pad<<<dim3(128 / 32, 1024 / 32), 256, 0, stream>>>(pW2, wt, 2 * DD, VV);
    gemm_bt<3><<<dim3(NTEST / 128, 1), 256, 0, stream>>>(hb, wt, pb2p, outpad, nullptr, NTEST, 128, 2 * DD);
    extract_out<<<(NTEST * VV + 255) / 256, 256, 0, stream>>>(outpad, (float*)d_out);
}

// Round 3
// 3447.112 us; speedup vs baseline: 3.0796x; 3.0796x over previous
//
#include <hip/hip_runtime.h>
#include <hip/hip_bf16.h>

// Problem constants
#define BB 4
#define TT 2048
#define TRAIN 1536
#define DD 512
#define HH 8
#define LL 12
#define FFD 2048
#define VV 100
#define DH 64
#define NT (BB*TT)            // 8192 tokens
#define NTEST (BB*(TT-TRAIN)) // 2048 test rows

typedef __bf16 bf16x8 __attribute__((ext_vector_type(8)));
typedef float  f32x4  __attribute__((ext_vector_type(4)));

// ---------------------------------------------------------------- emb + R add
__global__ __launch_bounds__(256) void emb_add(const float* __restrict__ R,
                                               const int* __restrict__ y,
                                               const float* __restrict__ emb,
                                               float* __restrict__ rep) {
    int idx = blockIdx.x * 256 + threadIdx.x;            // NT*DD total
    int d = idx & 511;
    int n = idx >> 9;
    int t = n & (TT - 1);
    int b = n >> 11;
    float val = R[idx];
    if (t < TRAIN) {
        int tok = y[b * TRAIN + t];
        val += emb[(size_t)tok * DD + d];
    }
    rep[idx] = val;
}

// ---------------------------------------------------------------- layernorm (fp32 in, bf16 out)
__global__ __launch_bounds__(256) void ln_kernel(const float* __restrict__ x,
                                                 const float* __restrict__ g,
                                                 const float* __restrict__ bta,
                                                 __bf16* __restrict__ out) {
    int row = blockIdx.x;
    int tid = threadIdx.x;
    const float* xr = x + (size_t)row * DD;
    float v0 = xr[tid], v1 = xr[tid + 256];
    float s = v0 + v1;
    float sq = v0 * v0 + v1 * v1;
#pragma unroll
    for (int off = 32; off; off >>= 1) {
        s  += __shfl_down(s, off);
        sq += __shfl_down(sq, off);
    }
    __shared__ float ss[4], ssq[4];
    if ((tid & 63) == 0) { ss[tid >> 6] = s; ssq[tid >> 6] = sq; }
    __syncthreads();
    float S  = ss[0] + ss[1] + ss[2] + ss[3];
    float SQ = ssq[0] + ssq[1] + ssq[2] + ssq[3];
    float mu  = S * (1.0f / DD);
    float var = SQ * (1.0f / DD) - mu * mu;
    float inv = rsqrtf(var + 1e-5f);
    __bf16* orow = out + (size_t)row * DD;
    orow[tid]       = (__bf16)((v0 - mu) * inv * g[tid]       + bta[tid]);
    orow[tid + 256] = (__bf16)((v1 - mu) * inv * g[tid + 256] + bta[tid + 256]);
}

// ---------------------------------------------------------------- rope table
__global__ __launch_bounds__(256) void rope_tab(float* __restrict__ ctab, float* __restrict__ stab) {
    int idx = blockIdx.x * 256 + threadIdx.x;  // TT*32
    int p = idx & 31, t = idx >> 5;
    double freq = exp(-((double)(2 * p) / 64.0) * log(100000.0));
    double ang = (double)t * freq;
    ctab[idx] = (float)cos(ang);
    stab[idx] = (float)sin(ang);
}

// ------------------------------------------- qkv split + rope -> [B,H,T,DH]
__global__ __launch_bounds__(256) void rope_split(const __bf16* __restrict__ qkv,
                                                  const float* __restrict__ ctab,
                                                  const float* __restrict__ stab,
                                                  __bf16* __restrict__ qo,
                                                  __bf16* __restrict__ ko,
                                                  __bf16* __restrict__ vo) {
    int idx = blockIdx.x * 256 + threadIdx.x;  // BB*TT*HH*32
    int p = idx & 31;
    int rest = idx >> 5;
    int h = rest & 7;  rest >>= 3;
    int t = rest & (TT - 1);
    int b = rest >> 11;
    const __bf16* base = qkv + (size_t)(b * TT + t) * (3 * DD) + h * DH;
    float c = ctab[t * 32 + p], s = stab[t * 32 + p];
    float x1 = (float)base[2 * p],       x2 = (float)base[2 * p + 1];
    float k1 = (float)base[DD + 2 * p],  k2 = (float)base[DD + 2 * p + 1];
    size_t ob = ((size_t)(b * HH + h) * TT + t) * DH;
    qo[ob + 2 * p]     = (__bf16)(x1 * c - x2 * s);
    qo[ob + 2 * p + 1] = (__bf16)(x1 * s + x2 * c);
    ko[ob + 2 * p]     = (__bf16)(k1 * c - k2 * s);
    ko[ob + 2 * p + 1] = (__bf16)(k1 * s + k2 * c);
    vo[ob + 2 * p]     = base[2 * DD + 2 * p];
    vo[ob + 2 * p + 1] = base[2 * DD + 2 * p + 1];
}

// ---------------------------------------------------------------- MFMA flash attention
// Grid (16, 32): 128-query tile per block, one (b,h) per blockIdx.y.
// All queries attend to the 1536 train keys; test queries (t>=TRAIN) also to self.
#define KS_STRIDE 72    // K/Q LDS row stride (bf16), 16B-aligned, bank-spread
#define PS_STRIDE 136   // P LDS row stride
#define VT_STRIDE 136   // V^T LDS row stride

__global__ __launch_bounds__(256, 2) void attn_mfma(const __bf16* __restrict__ q,
                                                    const __bf16* __restrict__ k,
                                                    const __bf16* __restrict__ v,
                                                    __bf16* __restrict__ obuf) {
    __shared__ __align__(16) __bf16 Qs[128 * KS_STRIDE];
    __shared__ __align__(16) __bf16 KPs[128 * PS_STRIDE];  // K chunk (stride 72) / P (stride 136)
    __shared__ __align__(16) __bf16 Vt[64 * VT_STRIDE];    // V^T [dh][key]
    __shared__ float sself[128];

    const int tid = threadIdx.x;
    const int bh = blockIdx.y;
    const int b = bh >> 3, hh = bh & 7;
    const size_t kbase = (size_t)bh * TT * DH;
    const int t0q = blockIdx.x * 128;
    const int w = tid >> 6;
    const int lane = tid & 63;
    const int l16 = lane & 15;
    const int quad = lane >> 4;

    // load Q tile (linear copy with row stride 72)
    {
        const __bf16* qg = q + kbase + (size_t)t0q * DH;
#pragma unroll
        for (int c = 0; c < 4; ++c) {
            int idx = c * 256 + tid;
            int row = idx >> 3, o8 = (idx & 7) * 8;
            *(uint4*)&Qs[row * KS_STRIDE + o8] = *(const uint4*)&qg[idx * 8];
        }
    }

    f32x4 oa[2][4] = {};
    float mst[2][4], lst[2][4];
#pragma unroll
    for (int mi = 0; mi < 2; ++mi)
#pragma unroll
        for (int r = 0; r < 4; ++r) { mst[mi][r] = -1e30f; lst[mi][r] = 0.f; }

    const int vkey = tid >> 1, vd0 = (tid & 1) * 32;

    for (int ci = 0; ci < TRAIN / 128; ++ci) {
        __syncthreads();  // prior chunk's PV reads done; safe to overwrite LDS
        // load K chunk (stride 72) + V chunk transposed
        {
            const __bf16* kg = k + kbase + (size_t)(ci * 128) * DH;
#pragma unroll
            for (int c = 0; c < 4; ++c) {
                int idx = c * 256 + tid;
                int row = idx >> 3, o8 = (idx & 7) * 8;
                *(uint4*)&KPs[row * KS_STRIDE + o8] = *(const uint4*)&kg[idx * 8];
            }
            const __bf16* vg = v + kbase + (size_t)(ci * 128 + vkey) * DH + vd0;
#pragma unroll
            for (int c = 0; c < 4; ++c) {
                uint4 u = *(const uint4*)&vg[c * 8];
                const __bf16* pb = (const __bf16*)&u;
#pragma unroll
                for (int j = 0; j < 8; ++j) Vt[(vd0 + c * 8 + j) * VT_STRIDE + vkey] = pb[j];
            }
        }
        __syncthreads();

        // S = Q @ K^T : wave w owns rows w*32..+31, all 128 cols
        f32x4 acc[2][8] = {};
#pragma unroll
        for (int ks = 0; ks < 2; ++ks) {
            bf16x8 qa[2], kb[8];
#pragma unroll
            for (int mi = 0; mi < 2; ++mi)
                qa[mi] = *(const bf16x8*)&Qs[(w * 32 + mi * 16 + l16) * KS_STRIDE + quad * 8 + ks * 32];
#pragma unroll
            for (int ni = 0; ni < 8; ++ni)
                kb[ni] = *(const bf16x8*)&KPs[(ni * 16 + l16) * KS_STRIDE + quad * 8 + ks * 32];
#pragma unroll
            for (int mi = 0; mi < 2; ++mi)
#pragma unroll
                for (int ni = 0; ni < 8; ++ni)
                    acc[mi][ni] = __builtin_amdgcn_mfma_f32_16x16x32_bf16(qa[mi], kb[ni], acc[mi][ni], 0, 0, 0);
        }

        // online softmax (row = w*32 + mi*16 + quad*4 + r)
        float alph[2][4];
#pragma unroll
        for (int mi = 0; mi < 2; ++mi)
#pragma unroll
            for (int ni = 0; ni < 8; ++ni) acc[mi][ni] *= 0.125f;
#pragma unroll
        for (int mi = 0; mi < 2; ++mi)
#pragma unroll
            for (int r = 0; r < 4; ++r) {
                float mx = acc[mi][0][r];
#pragma unroll
                for (int ni = 1; ni < 8; ++ni) mx = fmaxf(mx, acc[mi][ni][r]);
                mx = fmaxf(mx, __shfl_xor(mx, 1));
                mx = fmaxf(mx, __shfl_xor(mx, 2));
                mx = fmaxf(mx, __shfl_xor(mx, 4));
                mx = fmaxf(mx, __shfl_xor(mx, 8));
                float nm = fmaxf(mst[mi][r], mx);
                float al = __expf(mst[mi][r] - nm);
                float rs = 0.f;
#pragma unroll
                for (int ni = 0; ni < 8; ++ni) {
                    float pv = __expf(acc[mi][ni][r] - nm);
                    acc[mi][ni][r] = pv;
                    rs += pv;
                }
                rs += __shfl_xor(rs, 1);
                rs += __shfl_xor(rs, 2);
                rs += __shfl_xor(rs, 4);
                rs += __shfl_xor(rs, 8);
                mst[mi][r] = nm;
                lst[mi][r] = lst[mi][r] * al + rs;
                alph[mi][r] = al;
            }

        __syncthreads();  // all waves done reading K fragments before P overwrites
        // write P (C-layout -> LDS row-major, stride 136)
#pragma unroll
        for (int mi = 0; mi < 2; ++mi)
#pragma unroll
            for (int ni = 0; ni < 8; ++ni)
#pragma unroll
                for (int r = 0; r < 4; ++r)
                    KPs[(w * 32 + mi * 16 + quad * 4 + r) * PS_STRIDE + ni * 16 + l16] = (__bf16)acc[mi][ni][r];
        __syncthreads();

        // O = O*alpha + P @ V
#pragma unroll
        for (int mi = 0; mi < 2; ++mi)
#pragma unroll
            for (int ni = 0; ni < 4; ++ni)
#pragma unroll
                for (int r = 0; r < 4; ++r) oa[mi][ni][r] *= alph[mi][r];
#pragma unroll
        for (int ks = 0; ks < 4; ++ks) {
            bf16x8 pa[2], vb[4];
#pragma unroll
            for (int mi = 0; mi < 2; ++mi)
                pa[mi] = *(const bf16x8*)&KPs[(w * 32 + mi * 16 + l16) * PS_STRIDE + quad * 8 + ks * 32];
#pragma unroll
            for (int ni = 0; ni < 4; ++ni)
                vb[ni] = *(const bf16x8*)&Vt[(ni * 16 + l16) * VT_STRIDE + quad * 8 + ks * 32];
#pragma unroll
            for (int mi = 0; mi < 2; ++mi)
#pragma unroll
                for (int ni = 0; ni < 4; ++ni)
                    oa[mi][ni] = __builtin_amdgcn_mfma_f32_16x16x32_bf16(pa[mi], vb[ni], oa[mi][ni], 0, 0, 0);
        }
    }

    // self-key for test tiles (block-uniform branch)
    if (t0q >= TRAIN) {
        __syncthreads();
        {
            const __bf16* kg = k + kbase + (size_t)t0q * DH;
#pragma unroll
            for (int c = 0; c < 4; ++c) {
                int idx = c * 256 + tid;
                int row = idx >> 3, o8 = (idx & 7) * 8;
                *(uint4*)&KPs[row * KS_STRIDE + o8] = *(const uint4*)&kg[idx * 8];
            }
            const __bf16* vg = v + kbase + (size_t)(t0q + vkey) * DH + vd0;
#pragma unroll
            for (int c = 0; c < 4; ++c) {
                uint4 u = *(const uint4*)&vg[c * 8];
                const __bf16* pb = (const __bf16*)&u;
#pragma unroll
                for (int j = 0; j < 8; ++j) Vt[(vd0 + c * 8 + j) * VT_STRIDE + vkey] = pb[j];
            }
        }
        __syncthreads();
        {
            int row = tid >> 1, d0 = (tid & 1) * 32;
            float dacc = 0.f;
#pragma unroll
            for (int c = 0; c < 4; ++c) {
                uint4 uq = *(const uint4*)&Qs[row * KS_STRIDE + d0 + c * 8];
                uint4 uk = *(const uint4*)&KPs[row * KS_STRIDE + d0 + c * 8];
                const __bf16* pq = (const __bf16*)&uq;
                const __bf16* pk = (const __bf16*)&uk;
#pragma unroll
                for (int j = 0; j < 8; ++j) dacc += (float)pq[j] * (float)pk[j];
            }
            dacc += __shfl_xor(dacc, 1);
            sself[row] = dacc * 0.125f;
        }
        __syncthreads();
#pragma unroll
        for (int mi = 0; mi < 2; ++mi)
#pragma unroll
            for (int r = 0; r < 4; ++r) {
                int row = w * 32 + mi * 16 + quad * 4 + r;
                float ssv = sself[row];
                float nm = fmaxf(mst[mi][r], ssv);
                float al = __expf(mst[mi][r] - nm);
                float pp = __expf(ssv - nm);
                mst[mi][r] = nm;
                lst[mi][r] = lst[mi][r] * al + pp;
#pragma unroll
                for (int ni = 0; ni < 4; ++ni)
                    oa[mi][ni][r] = oa[mi][ni][r] * al + pp * (float)Vt[(ni * 16 + l16) * VT_STRIDE + row];
            }
    }

    // normalize + store
#pragma unroll
    for (int mi = 0; mi < 2; ++mi)
#pragma unroll
        for (int r = 0; r < 4; ++r) {
            float inv = 1.f / lst[mi][r];
            int trow = t0q + w * 32 + mi * 16 + quad * 4 + r;
            __bf16* op = obuf + ((size_t)(b * TT) + trow) * DD + hh * 64;
#pragma unroll
            for (int ni = 0; ni < 4; ++ni)
                op[ni * 16 + l16] = (__bf16)(oa[mi][ni][r] * inv);
        }
}

// ------------------------------------- transpose fp32->bf16 (with N-pad/zero-fill)
__global__ __launch_bounds__(256) void transpose_pad(const float* __restrict__ src,  // [K,N] fp32
                                                     __bf16* __restrict__ dst,       // [Npad,K] bf16
                                                     int K, int N) {
    __shared__ __bf16 t[32][33];
    int n0 = blockIdx.x * 32, k0 = blockIdx.y * 32;
    int tx = threadIdx.x & 31, ty = threadIdx.x >> 5;  // ty 0..7
#pragma unroll
    for (int i = 0; i < 4; ++i) {
        int nn = n0 + tx;
        t[ty + i * 8][tx] = (nn < N) ? (__bf16)src[(size_t)(k0 + ty + i * 8) * N + nn] : (__bf16)0.f;
    }
    __syncthreads();
#pragma unroll
    for (int i = 0; i < 4; ++i) {
        dst[(size_t)(n0 + ty + i * 8) * K + k0 + tx] = t[tx][ty + i * 8];
    }
}

// ---------------------------------------------------------------- MFMA GEMM (Bt input)
// C[M,N] = A[M,K] * B[K,N] + bias, with Bt = B^T given as [N,K] (bf16).
// EP=0: bf16 store; EP=1: gelu(tanh) then bf16 store; EP=2: resid += (fp32);
// EP=3: plain fp32 store to resid.
template <int EP>
__global__ __launch_bounds__(256) void gemm_bt(const __bf16* __restrict__ A,
                                               const __bf16* __restrict__ Bt,
                                               const float* __restrict__ bias,
                                               float* __restrict__ resid,
                                               __bf16* __restrict__ Cout,
                                               int M, int N, int K) {
    __shared__ __align__(16) __bf16 As[128 * 32];
    __shared__ __align__(16) __bf16 Bs[128 * 32];
    const int tid = threadIdx.x;
    const int m0 = blockIdx.x * 128;
    const int n0 = blockIdx.y * 128;
    const int lane = tid & 63;
    const int w = tid >> 6;
    const int wm = (w >> 1) * 64, wn = (w & 1) * 64;
    const int lrow = lane & 15;
    const int kq = (lane >> 4) * 8;

    f32x4 acc[4][4] = {};
    const int r0 = tid >> 2,         o0 = (tid & 3) * 8;
    const int r1 = (tid + 256) >> 2, o1 = o0;

    const int nk = K >> 5;
    for (int kt = 0; kt < nk; ++kt) {
        const int k0 = kt << 5;
        *(uint4*)&As[r0 * 32 + o0] = *(const uint4*)&A[(size_t)(m0 + r0) * K + k0 + o0];
        *(uint4*)&As[r1 * 32 + o1] = *(const uint4*)&A[(size_t)(m0 + r1) * K + k0 + o1];
        *(uint4*)&Bs[r0 * 32 + o0] = *(const uint4*)&Bt[(size_t)(n0 + r0) * K + k0 + o0];
        *(uint4*)&Bs[r1 * 32 + o1] = *(const uint4*)&Bt[(size_t)(n0 + r1) * K + k0 + o1];
        __syncthreads();
        bf16x8 afr[4], bfr[4];
#pragma unroll
        for (int i = 0; i < 4; ++i) {
            afr[i] = *(const bf16x8*)&As[(wm + i * 16 + lrow) * 32 + kq];
            bfr[i] = *(const bf16x8*)&Bs[(wn + i * 16 + lrow) * 32 + kq];
        }
#pragma unroll
        for (int mi = 0; mi < 4; ++mi)
#pragma unroll
            for (int ni = 0; ni < 4; ++ni)
                acc[mi][ni] = __builtin_amdgcn_mfma_f32_16x16x32_bf16(afr[mi], bfr[ni], acc[mi][ni], 0, 0, 0);
        __syncthreads();
    }

    const int crow = (lane >> 4) * 4;
    const int ccol = lane & 15;
#pragma unroll
    for (int mi = 0; mi < 4; ++mi) {
#pragma unroll
        for (int ni = 0; ni < 4; ++ni) {
            int gn = n0 + wn + ni * 16 + ccol;
            float bv = bias[gn];
#pragma unroll
            for (int r = 0; r < 4; ++r) {
                int gm = m0 + wm + mi * 16 + crow + r;
                float vvv = acc[mi][ni][r] + bv;
                if constexpr (EP == 1) {
                    float x = vvv;
                    vvv = 0.5f * x * (1.f + tanhf(0.7978845608f * (x + 0.044715f * x * x * x)));
                }
                if constexpr (EP == 2) {
                    resid[(size_t)gm * N + gn] += vvv;
                } else if constexpr (EP == 3) {
                    resid[(size_t)gm * N + gn] = vvv;
                } else {
                    Cout[(size_t)gm * N + gn] = (__bf16)vvv;
                }
            }
        }
    }
}

// ---------------------------------------------------------------- post-layer helpers
__global__ __launch_bounds__(256) void cast_test(const float* __restrict__ rep, __bf16* __restrict__ testb) {
    int idx = blockIdx.x * 256 + threadIdx.x;  // NTEST*DD
    int d = idx & 511;
    int i = idx >> 9;
    int ttk = i & 511;
    int b = i >> 9;
    testb[idx] = (__bf16)rep[(size_t)(b * TT + TRAIN + ttk) * DD + d];
}

__global__ void pad_bias(const float* __restrict__ pb2, float* __restrict__ pb2p) {
    int t = threadIdx.x;
    if (t < 128) pb2p[t] = (t < VV) ? pb2[t] : 0.f;
}

__global__ __launch_bounds__(256) void extract_out(const float* __restrict__ outpad, float* __restrict__ out) {
    int idx = blockIdx.x * 256 + threadIdx.x;  // NTEST*VV = 204800
    if (idx < NTEST * VV) {
        int i = idx / VV, j = idx - i * VV;
        out[idx] = outpad[i * 128 + j];
    }
}

// ---------------------------------------------------------------- launcher
extern "C" void kernel_launch(void* const* d_in, const int* in_sizes, int n_in,
                              void* d_out, int out_size, void* d_ws, size_t ws_size,
                              hipStream_t stream) {
    const float* R    = (const float*)d_in[0];
    const int*   y    = (const int*)d_in[1];
    const float* emb  = (const float*)d_in[2];
    const float* Wqkv = (const float*)d_in[3];
    const float* bqkv = (const float*)d_in[4];
    const float* Wo   = (const float*)d_in[5];
    const float* bo   = (const float*)d_in[6];
    const float* ln1g = (const float*)d_in[7];
    const float* ln1b = (const float*)d_in[8];
    const float* ln2g = (const float*)d_in[9];
    const float* ln2b = (const float*)d_in[10];
    const float* W1   = (const float*)d_in[11];
    const float* b1   = (const float*)d_in[12];
    const float* W2   = (const float*)d_in[13];
    const float* b2   = (const float*)d_in[14];
    const float* pW1  = (const float*)d_in[15];
    const float* pb1  = (const float*)d_in[16];
    const float* pW2  = (const float*)d_in[17];
    const float* pb2  = (const float*)d_in[18];

    // workspace carve-up
    char* p = (char*)d_ws;
    float* rep   = (float*)p;  p += (size_t)NT * DD * 4;        // 16.78 MB
    __bf16* hbuf = (__bf16*)p; p += (size_t)NT * DD * 2;        // 8.39 MB
    __bf16* qkv  = (__bf16*)p;                                  // union with ffb
    __bf16* ffb  = qkv;        p += (size_t)NT * FFD * 2;       // 33.55 MB
    __bf16* qb   = (__bf16*)p; p += (size_t)NT * DD * 2;        // 8.39 MB
    __bf16* kb   = (__bf16*)p; p += (size_t)NT * DD * 2;
    __bf16* vb   = (__bf16*)p; p += (size_t)NT * DD * 2;
    __bf16* obuf = (__bf16*)p; p += (size_t)NT * DD * 2;
    __bf16* wt   = (__bf16*)p; p += (size_t)2048 * 512 * 2;     // 2 MB transposed-weight scratch
    float* ctab  = (float*)p;  p += (size_t)TT * 32 * 4;
    float* stab  = (float*)p;  p += (size_t)TT * 32 * 4;
    float* pb2p  = (float*)p;  p += 512;
    // post-layer aliases (hbuf/qb/obuf dead after the layer loop)
    __bf16* testb  = hbuf;                 // 2 MB
    __bf16* hb     = obuf;                 // 4 MB
    float*  outpad = (float*)qb;           // 1 MB

    emb_add<<<NT * DD / 256, 256, 0, stream>>>(R, y, emb, rep);
    rope_tab<<<TT * 32 / 256, 256, 0, stream>>>(ctab, stab);

    for (int l = 0; l < LL; ++l) {
        ln_kernel<<<NT, 256, 0, stream>>>(rep, ln1g + l * DD, ln1b + l * DD, hbuf);
        transpose_pad<<<dim3(1536 / 32, 512 / 32), 256, 0, stream>>>(Wqkv + (size_t)l * DD * 3 * DD, wt, DD, 3 * DD);
        gemm_bt<0><<<dim3(NT / 128, 1536 / 128), 256, 0, stream>>>(hbuf, wt, bqkv + l * 3 * DD, nullptr, qkv, NT, 3 * DD, DD);
        rope_split<<<BB * TT * HH * 32 / 256, 256, 0, stream>>>(qkv, ctab, stab, qb, kb, vb);
        attn_mfma<<<dim3(TT / 128, BB * HH), 256, 0, stream>>>(qb, kb, vb, obuf);
        transpose_pad<<<dim3(512 / 32, 512 / 32), 256, 0, stream>>>(Wo + (size_t)l * DD * DD, wt, DD, DD);
        gemm_bt<2><<<dim3(NT / 128, 512 / 128), 256, 0, stream>>>(obuf, wt, bo + l * DD, rep, nullptr, NT, DD, DD);
        ln_kernel<<<NT, 256, 0, stream>>>(rep, ln2g + l * DD, ln2b + l * DD, hbuf);
        transpose_pad<<<dim3(2048 / 32, 512 / 32), 256, 0, stream>>>(W1 + (size_t)l * DD * FFD, wt, DD, FFD);
        gemm_bt<1><<<dim3(NT / 128, FFD / 128), 256, 0, stream>>>(hbuf, wt, b1 + l * FFD, nullptr, ffb, NT, FFD, DD);
        transpose_pad<<<dim3(512 / 32, 2048 / 32), 256, 0, stream>>>(W2 + (size_t)l * FFD * DD, wt, FFD, DD);
        gemm_bt<2><<<dim3(NT / 128, 512 / 128), 256, 0, stream>>>(ffb, wt, b2 + l * DD, rep, nullptr, NT, DD, FFD);
    }

    cast_test<<<NTEST * DD / 256, 256, 0, stream>>>(rep, testb);
    transpose_pad<<<dim3(1024 / 32, 512 / 32), 256, 0, stream>>>(pW1, wt, DD, 2 * DD);
    gemm_bt<1><<<dim3(NTEST / 128, 1024 / 128), 256, 0, stream>>>(testb, wt, pb1, nullptr, hb, NTEST, 2 * DD, DD);
    pad_bias<<<1, 128, 0, stream>>>(pb2, pb2p);
    transpose_pad<<<dim3(128 / 32, 1024 / 32), 256, 0, stream>>>(pW2, wt, 2 * DD, VV);
    gemm_bt<3><<<dim3(NTEST / 128, 1), 256, 0, stream>>>(hb, wt, pb2p, outpad, nullptr, NTEST, 128, 2 * DD);
    extract_out<<<(NTEST * VV + 255) / 256, 256, 0, stream>>>(outpad, (float*)d_out);
}